// Round 1
// baseline (6886.118 us; speedup 1.0000x reference)
//
#include <hip/hip_runtime.h>

#define B_  8
#define S_  1024
#define D_  768
#define H_  12
#define DK_ 64
#define NEG_ -1e12f

constexpr int JT = 16;   // j rows per attention block

// ---------------------------------------------------------------------------
// Fused QKV projection: C[row,col] = x[row,:] @ W[:,col] + b[col]
// rows = B*S = 8192, cols = H*DK = 768.  Output layout [B,H,S,DK].
// blockIdx.z selects q/k/v.  64x64 tile per block, 256 threads, 4x4 per thread.
// ---------------------------------------------------------------------------
__global__ __launch_bounds__(256) void qkv_gemm(
    const float* __restrict__ x,
    const float* __restrict__ Wq, const float* __restrict__ bq,
    const float* __restrict__ Wk, const float* __restrict__ bk,
    const float* __restrict__ Wv, const float* __restrict__ bv,
    float* __restrict__ qo, float* __restrict__ ko, float* __restrict__ vo)
{
    const float* W; const float* bias; float* out;
    if (blockIdx.z == 0)      { W = Wq; bias = bq; out = qo; }
    else if (blockIdx.z == 1) { W = Wk; bias = bk; out = ko; }
    else                      { W = Wv; bias = bv; out = vo; }

    const int row0 = blockIdx.x * 64;
    const int col0 = blockIdx.y * 64;
    const int t  = threadIdx.x;
    const int tx = t & 15, ty = t >> 4;

    __shared__ float Xs[64][17];   // +1 pad: kills 4-way bank conflict on row reads
    __shared__ float Ws[16][68];

    float acc[4][4] = {};

    for (int kt = 0; kt < D_; kt += 16) {
        {   // stage X tile 64x16
            const int r = t >> 2, c = (t & 3) * 4;
            const float4 xv = *(const float4*)&x[(size_t)(row0 + r) * D_ + kt + c];
            Xs[r][c] = xv.x; Xs[r][c+1] = xv.y; Xs[r][c+2] = xv.z; Xs[r][c+3] = xv.w;
        }
        {   // stage W tile 16x64
            const int r = t >> 4, c = (t & 15) * 4;
            const float4 wv = *(const float4*)&W[(size_t)(kt + r) * D_ + col0 + c];
            Ws[r][c] = wv.x; Ws[r][c+1] = wv.y; Ws[r][c+2] = wv.z; Ws[r][c+3] = wv.w;
        }
        __syncthreads();
        #pragma unroll
        for (int kk = 0; kk < 16; ++kk) {
            float xr[4], wc[4];
            #pragma unroll
            for (int i = 0; i < 4; ++i) xr[i] = Xs[ty*4+i][kk];
            #pragma unroll
            for (int j = 0; j < 4; ++j) wc[j] = Ws[kk][tx*4+j];
            #pragma unroll
            for (int i = 0; i < 4; ++i)
                #pragma unroll
                for (int j = 0; j < 4; ++j)
                    acc[i][j] += xr[i] * wc[j];
        }
        __syncthreads();
    }

    #pragma unroll
    for (int i = 0; i < 4; ++i) {
        const int row = row0 + ty*4 + i;
        const int b = row >> 10, s = row & 1023;
        #pragma unroll
        for (int j = 0; j < 4; ++j) {
            const int col = col0 + tx*4 + j;
            const int h = col >> 6, dk = col & 63;
            out[(((size_t)(b * H_ + h)) * S_ + s) * DK_ + dk] = acc[i][j] + bias[col];
        }
    }
}

// ---------------------------------------------------------------------------
// Attention: block = (bh, j-tile of 16).  grid (96, 64), bh fastest so the 96
// blocks sharing a j-tile are co-resident -> pb[j-tile] shared via L2.
// score[j,k] = q[j]·(K[k] + pb[j,k]) / 8 + (1-vmask[k])*NEG
// out[j,d]   = sum_k softmax(score)[j,k] * (V[k,d] + pb[j,k,d])
// ---------------------------------------------------------------------------
__global__ __launch_bounds__(256) void attn_kernel(
    const float* __restrict__ q,    // [B*H, S, 64]
    const float* __restrict__ kk_,  // [B*H, S, 64]
    const float* __restrict__ vv_,  // [B*H, S, 64]
    const float* __restrict__ pb,   // [S, S, 64]
    const float* __restrict__ vmask,// [B, S]
    float* __restrict__ omid)       // [B, S, 768]
{
    const int bh = blockIdx.x;            // 0..95
    const int b  = bh / H_;
    const int h  = bh % H_;
    const int j0 = blockIdx.y * JT;
    const int t  = threadIdx.x;

    __shared__ float Sc[JT][S_ + 1];      // scores, +1 pad (65.6 KB, gfx950 LDS ok)
    __shared__ float inv_sum[JT];

    // ---- phase 1: scores. thread t: row jj = t>>4, columns k = (t&15) + 16*ki
    {
        const int jj    = t >> 4;
        const int kbase = t & 15;

        // Q row for this thread fully in registers (64 VGPRs, read once)
        float Qreg[64];
        {
            const float4* Qg = (const float4*)(q + ((size_t)bh * S_ + (j0 + jj)) * DK_);
            #pragma unroll
            for (int c = 0; c < 16; ++c) {
                const float4 qv = Qg[c];
                Qreg[c*4+0] = qv.x; Qreg[c*4+1] = qv.y;
                Qreg[c*4+2] = qv.z; Qreg[c*4+3] = qv.w;
            }
        }

        const float* Kbase = kk_ + (size_t)bh * S_ * DK_;
        const float* Pbase = pb + (size_t)(j0 + jj) * S_ * DK_;
        const float* vmb   = vmask + (size_t)b * S_;

        for (int ki = 0; ki < 64; ++ki) {
            const int k = kbase + 16 * ki;
            const float4* Kr = (const float4*)(Kbase + (size_t)k * DK_);
            const float4* Pr = (const float4*)(Pbase + (size_t)k * DK_);
            float acc = 0.f;
            #pragma unroll
            for (int c = 0; c < 16; ++c) {
                const float4 kv = Kr[c];
                const float4 pv = Pr[c];
                acc += (kv.x + pv.x) * Qreg[c*4+0];
                acc += (kv.y + pv.y) * Qreg[c*4+1];
                acc += (kv.z + pv.z) * Qreg[c*4+2];
                acc += (kv.w + pv.w) * Qreg[c*4+3];
            }
            Sc[jj][k] = acc * 0.125f + (1.0f - vmb[k]) * NEG_;
        }
    }
    __syncthreads();

    // ---- phase 2: softmax per row (wave w handles rows w, w+4, w+8, w+12)
    {
        const int lane = t & 63;
        const int w    = t >> 6;
        for (int i = 0; i < 4; ++i) {
            const int jj = w + 4 * i;
            float m = -3.0e38f;
            for (int c = lane; c < S_; c += 64) m = fmaxf(m, Sc[jj][c]);
            #pragma unroll
            for (int off = 32; off > 0; off >>= 1) m = fmaxf(m, __shfl_xor(m, off));
            float sum = 0.f;
            for (int c = lane; c < S_; c += 64) {
                const float e = __expf(Sc[jj][c] - m);
                Sc[jj][c] = e;
                sum += e;
            }
            #pragma unroll
            for (int off = 32; off > 0; off >>= 1) sum += __shfl_xor(sum, off);
            if (lane == 0) inv_sum[jj] = 1.0f / sum;
        }
    }
    __syncthreads();

    // ---- phase 3: output. wave w: rows {w,w+4,w+8,w+12}, lane = d
    {
        const int d = t & 63;
        const int w = t >> 6;
        const float* Vb = vv_ + (size_t)bh * S_ * DK_ + d;
        float oacc[4] = {0.f, 0.f, 0.f, 0.f};
        for (int k = 0; k < S_; ++k) {
            const float vval = Vb[(size_t)k * DK_];
            #pragma unroll
            for (int i = 0; i < 4; ++i) {
                const int jj = w + 4 * i;
                const float pval = pb[((size_t)(j0 + jj) * S_ + k) * DK_ + d];
                oacc[i] += Sc[jj][k] * (vval + pval);
            }
        }
        #pragma unroll
        for (int i = 0; i < 4; ++i) {
            const int jj = w + 4 * i;
            omid[((size_t)b * S_ + (j0 + jj)) * D_ + h * DK_ + d] = oacc[i] * inv_sum[jj];
        }
    }
}

// ---------------------------------------------------------------------------
// Output projection: out[row,:] = (omid[row,:] @ Wo + bo) * q_mask[row]
// ---------------------------------------------------------------------------
__global__ __launch_bounds__(256) void out_gemm(
    const float* __restrict__ a,    // omid [8192,768]
    const float* __restrict__ W,    // Wo [768,768]
    const float* __restrict__ bias, // bo
    const float* __restrict__ qm,   // q_mask [8192]
    float* __restrict__ out)        // [8192,768]
{
    const int row0 = blockIdx.x * 64;
    const int col0 = blockIdx.y * 64;
    const int t  = threadIdx.x;
    const int tx = t & 15, ty = t >> 4;

    __shared__ float Xs[64][17];
    __shared__ float Ws[16][68];

    float acc[4][4] = {};

    for (int kt = 0; kt < D_; kt += 16) {
        {
            const int r = t >> 2, c = (t & 3) * 4;
            const float4 xv = *(const float4*)&a[(size_t)(row0 + r) * D_ + kt + c];
            Xs[r][c] = xv.x; Xs[r][c+1] = xv.y; Xs[r][c+2] = xv.z; Xs[r][c+3] = xv.w;
        }
        {
            const int r = t >> 4, c = (t & 15) * 4;
            const float4 wv = *(const float4*)&W[(size_t)(kt + r) * D_ + col0 + c];
            Ws[r][c] = wv.x; Ws[r][c+1] = wv.y; Ws[r][c+2] = wv.z; Ws[r][c+3] = wv.w;
        }
        __syncthreads();
        #pragma unroll
        for (int kk = 0; kk < 16; ++kk) {
            float xr[4], wc[4];
            #pragma unroll
            for (int i = 0; i < 4; ++i) xr[i] = Xs[ty*4+i][kk];
            #pragma unroll
            for (int j = 0; j < 4; ++j) wc[j] = Ws[kk][tx*4+j];
            #pragma unroll
            for (int i = 0; i < 4; ++i)
                #pragma unroll
                for (int j = 0; j < 4; ++j)
                    acc[i][j] += xr[i] * wc[j];
        }
        __syncthreads();
    }

    #pragma unroll
    for (int i = 0; i < 4; ++i) {
        const int row = row0 + ty*4 + i;
        const float qmv = qm[row];
        #pragma unroll
        for (int j = 0; j < 4; ++j) {
            const int col = col0 + tx*4 + j;
            out[(size_t)row * D_ + col] = (acc[i][j] + bias[col]) * qmv;
        }
    }
}

extern "C" void kernel_launch(void* const* d_in, const int* in_sizes, int n_in,
                              void* d_out, int out_size, void* d_ws, size_t ws_size,
                              hipStream_t stream) {
    const float* x  = (const float*)d_in[0];
    const float* Wq = (const float*)d_in[1];
    const float* bq = (const float*)d_in[2];
    const float* Wk = (const float*)d_in[3];
    const float* bk = (const float*)d_in[4];
    const float* Wv = (const float*)d_in[5];
    const float* bv = (const float*)d_in[6];
    const float* Wo = (const float*)d_in[7];
    const float* bo = (const float*)d_in[8];
    const float* pb = (const float*)d_in[9];
    const float* qm = (const float*)d_in[10];
    const float* vm = (const float*)d_in[11];
    float* out = (float*)d_out;

    float* ws = (float*)d_ws;
    const size_t NQ = (size_t)B_ * H_ * S_ * DK_;   // 6,291,456
    float* qb = ws;
    float* kb = ws + NQ;
    float* vb = ws + 2 * NQ;
    float* om = ws + 3 * NQ;    // [B,S,768]  (total ws use: ~100.7 MB)

    dim3 g1(128, 12, 3);
    qkv_gemm<<<g1, 256, 0, stream>>>(x, Wq, bq, Wk, bk, Wv, bv, qb, kb, vb);

    dim3 g2(96, 64);            // bh fastest -> same j-tile co-resident
    attn_kernel<<<g2, 256, 0, stream>>>(qb, kb, vb, pb, vm, om);

    dim3 g3(128, 12);
    out_gemm<<<g3, 256, 0, stream>>>(om, Wo, bo, qm, out);
}

// Round 2
// 1082.506 us; speedup vs baseline: 6.3613x; 6.3613x over previous
//
#include <hip/hip_runtime.h>

#define B_  8
#define S_  1024
#define D_  768
#define H_  12
#define DK_ 64
#define BH_ 96

typedef _Float16 f16;
typedef _Float16 f16x8 __attribute__((ext_vector_type(8)));
typedef _Float16 f16x4 __attribute__((ext_vector_type(4)));
typedef float    f32x4 __attribute__((ext_vector_type(4)));

#define MFMA16(a, b, c) __builtin_amdgcn_mfma_f32_16x16x32_f16((a), (b), (c), 0, 0, 0)

// ---- LDS swizzle helpers: XOR bits 4..6 of byte offset with f(row) ---------
__device__ __forceinline__ int swz(int row) { return ((row ^ (row >> 3)) & 7) << 4; }

__device__ __forceinline__ f16x8 lds_read8(const f16* base, int row, int rowbytes, int colbyte) {
    const char* p = (const char*)base + row * rowbytes + (colbyte ^ swz(row));
    return *(const f16x8*)p;
}
__device__ __forceinline__ void lds_write8(f16* base, int row, int rowbytes, int colbyte, f16x8 v) {
    char* p = (char*)base + row * rowbytes + (colbyte ^ swz(row));
    *(f16x8*)p = v;
}
__device__ __forceinline__ void lds_write4(f16* base, int row, int rowbytes, int colbyte, f16x4 v) {
    char* p = (char*)base + row * rowbytes + (colbyte ^ swz(row));
    *(f16x4*)p = v;
}
__device__ __forceinline__ void lds_write1(f16* base, int row, int rowbytes, int colbyte, f16 v) {
    char* p = (char*)base + row * rowbytes + (colbyte ^ swz(row));
    *(f16*)p = v;
}
__device__ __forceinline__ f16 lds_read1(const f16* base, int row, int rowbytes, int colbyte) {
    const char* p = (const char*)base + row * rowbytes + (colbyte ^ swz(row));
    return *(const f16*)p;
}

// ---------------------------------------------------------------------------
// Pass 1: QKV projection (fp32 compute), f16 output in [bh][s][64] layout.
// ---------------------------------------------------------------------------
__global__ __launch_bounds__(256) void qkv_gemm(
    const float* __restrict__ x,
    const float* __restrict__ Wq, const float* __restrict__ bq,
    const float* __restrict__ Wk, const float* __restrict__ bk,
    const float* __restrict__ Wv, const float* __restrict__ bv,
    f16* __restrict__ qo, f16* __restrict__ ko, f16* __restrict__ vo)
{
    const float* W; const float* bias; f16* out;
    if (blockIdx.z == 0)      { W = Wq; bias = bq; out = qo; }
    else if (blockIdx.z == 1) { W = Wk; bias = bk; out = ko; }
    else                      { W = Wv; bias = bv; out = vo; }

    const int row0 = blockIdx.x * 64;
    const int col0 = blockIdx.y * 64;
    const int t  = threadIdx.x;
    const int tx = t & 15, ty = t >> 4;

    __shared__ __attribute__((aligned(16))) float Xs[64][17];
    __shared__ __attribute__((aligned(16))) float Ws[16][68];

    float acc[4][4] = {};

    for (int kt = 0; kt < D_; kt += 16) {
        {
            const int r = t >> 2, c = (t & 3) * 4;
            const float4 xv = *(const float4*)&x[(size_t)(row0 + r) * D_ + kt + c];
            Xs[r][c] = xv.x; Xs[r][c+1] = xv.y; Xs[r][c+2] = xv.z; Xs[r][c+3] = xv.w;
        }
        {
            const int r = t >> 4, c = (t & 15) * 4;
            const float4 wv = *(const float4*)&W[(size_t)(kt + r) * D_ + col0 + c];
            Ws[r][c] = wv.x; Ws[r][c+1] = wv.y; Ws[r][c+2] = wv.z; Ws[r][c+3] = wv.w;
        }
        __syncthreads();
        #pragma unroll
        for (int kk = 0; kk < 16; ++kk) {
            float xr[4], wc[4];
            #pragma unroll
            for (int i = 0; i < 4; ++i) xr[i] = Xs[ty*4+i][kk];
            #pragma unroll
            for (int j = 0; j < 4; ++j) wc[j] = Ws[kk][tx*4+j];
            #pragma unroll
            for (int i = 0; i < 4; ++i)
                #pragma unroll
                for (int j = 0; j < 4; ++j)
                    acc[i][j] += xr[i] * wc[j];
        }
        __syncthreads();
    }

    #pragma unroll
    for (int i = 0; i < 4; ++i) {
        const int row = row0 + ty*4 + i;
        const int b = row >> 10, s = row & 1023;
        #pragma unroll
        for (int j = 0; j < 4; ++j) {
            const int col = col0 + tx*4 + j;
            const int h = col >> 6, dk = col & 63;
            out[(((size_t)(b * H_ + h)) * S_ + s) * DK_ + dk] = (f16)(acc[i][j] + bias[col]);
        }
    }
}

// ---------------------------------------------------------------------------
// Pass 2: S2[bh][j][k] = Q[bh,j,:] . pb[j,k,:]  (per-j GEMM, M=96,N=1024,K=64)
// grid (512 j_local, 4 n-tiles of 256). pb read from fp32, converted in LDS.
// ---------------------------------------------------------------------------
__global__ __launch_bounds__(256) void s2_gemm(
    const f16* __restrict__ Qb, const float* __restrict__ pb,
    f16* __restrict__ S2, int jbase)
{
    const int jl = blockIdx.x;
    const int j  = jbase + jl;
    const int n0 = blockIdx.y * 256;
    const int t = threadIdx.x, l = t & 63, w = t >> 6;

    __shared__ __attribute__((aligned(16))) f16 Qs[96 * 64];    // rowbytes 128
    __shared__ __attribute__((aligned(16))) f16 Ps[256 * 64];   // rowbytes 128

    for (int idx = t; idx < 96 * 8; idx += 256) {
        const int r = idx >> 3, c8 = idx & 7;
        f16x8 v = *(const f16x8*)(Qb + ((size_t)r * S_ + j) * DK_ + c8 * 8);
        lds_write8(Qs, r, 128, c8 * 16, v);
    }
    for (int idx = t; idx < 256 * 16; idx += 256) {
        const int r = idx >> 4, c4 = idx & 15;
        const float4 v = *(const float4*)(pb + ((size_t)j * S_ + n0 + r) * DK_ + c4 * 4);
        f16x4 h; h[0] = (f16)v.x; h[1] = (f16)v.y; h[2] = (f16)v.z; h[3] = (f16)v.w;
        lds_write4(Ps, r, 128, c4 * 8, h);
    }
    __syncthreads();

    f32x4 acc[6][4] = {};
    #pragma unroll
    for (int s = 0; s < 4; ++s) {
        const int nrow = w * 64 + s * 16 + (l & 15);
        const f16x8 b0 = lds_read8(Ps, nrow, 128, (l >> 4) * 16);
        const f16x8 b1 = lds_read8(Ps, nrow, 128, 64 + (l >> 4) * 16);
        #pragma unroll
        for (int mi = 0; mi < 6; ++mi) {
            const int mrow = mi * 16 + (l & 15);
            const f16x8 a0 = lds_read8(Qs, mrow, 128, (l >> 4) * 16);
            const f16x8 a1 = lds_read8(Qs, mrow, 128, 64 + (l >> 4) * 16);
            acc[mi][s] = MFMA16(a0, b0, acc[mi][s]);
            acc[mi][s] = MFMA16(a1, b1, acc[mi][s]);
        }
    }

    #pragma unroll
    for (int mi = 0; mi < 6; ++mi)
        #pragma unroll
        for (int q = 0; q < 4; ++q) {
            const int bh = mi * 16 + (l >> 4) * 4 + q;
            const size_t base = (size_t)bh * (512 * 1024) + (size_t)jl * 1024;
            #pragma unroll
            for (int s = 0; s < 4; ++s) {
                const int k = n0 + w * 64 + s * 16 + (l & 15);
                S2[base + k] = (f16)acc[mi][s][q];
            }
        }
}

// ---------------------------------------------------------------------------
// Pass 3: scores = (QK^T + S2)/8 + mask; exact softmax; write normalized A
// (f16, in place over S2). block = (bh, 16 j rows), full k in registers.
// ---------------------------------------------------------------------------
__global__ __launch_bounds__(256) void attn_sm(
    const f16* __restrict__ Qb, const f16* __restrict__ Kb,
    const float* __restrict__ vmask, f16* __restrict__ S2A, int jbase)
{
    const int bh = blockIdx.x, b = bh / H_;
    const int jl0 = blockIdx.y * 16;
    const int j0 = jbase + jl0;
    const int t = threadIdx.x, l = t & 63, w = t >> 6;

    __shared__ __attribute__((aligned(16))) f16 Ks[128 * 64];     // 16 KB
    __shared__ __attribute__((aligned(16))) f16 S2s[16 * 1024];   // 32 KB, rowbytes 2048
    __shared__ float vmneg[1024];
    __shared__ float redm[4][16], reds[4][16];

    for (int idx = t; idx < 16 * 128; idx += 256) {
        const int r = idx >> 7, c8 = idx & 127;
        f16x8 v = *(const f16x8*)(S2A + (size_t)bh * (512 * 1024) + (size_t)(jl0 + r) * 1024 + c8 * 8);
        lds_write8(S2s, r, 2048, c8 * 16, v);
    }
    for (int k = t; k < 1024; k += 256)
        vmneg[k] = (vmask[(size_t)b * S_ + k] - 1.0f) * 1e12f;

    const f16x8 aq0 = *(const f16x8*)(Qb + ((size_t)bh * S_ + j0 + (l & 15)) * DK_ + (l >> 4) * 8);
    const f16x8 aq1 = *(const f16x8*)(Qb + ((size_t)bh * S_ + j0 + (l & 15)) * DK_ + 32 + (l >> 4) * 8);

    f32x4 acc[16] = {};
    #pragma unroll
    for (int c = 0; c < 8; ++c) {
        __syncthreads();
        for (int idx = t; idx < 128 * 8; idx += 256) {
            const int r = idx >> 3, c8 = idx & 7;
            f16x8 v = *(const f16x8*)(Kb + ((size_t)bh * S_ + c * 128 + r) * DK_ + c8 * 8);
            lds_write8(Ks, r, 128, c8 * 16, v);
        }
        __syncthreads();
        #pragma unroll
        for (int s = 0; s < 2; ++s) {
            const int krow = w * 32 + s * 16 + (l & 15);
            const f16x8 b0 = lds_read8(Ks, krow, 128, (l >> 4) * 16);
            const f16x8 b1 = lds_read8(Ks, krow, 128, 64 + (l >> 4) * 16);
            acc[c * 2 + s] = MFMA16(aq0, b0, acc[c * 2 + s]);
            acc[c * 2 + s] = MFMA16(aq1, b1, acc[c * 2 + s]);
        }
    }

    // combine + mask, per-row max
    float mrow[4] = {-3e38f, -3e38f, -3e38f, -3e38f};
    #pragma unroll
    for (int f = 0; f < 16; ++f) {
        const int k = (f >> 1) * 128 + w * 32 + (f & 1) * 16 + (l & 15);
        const float vm = vmneg[k];
        #pragma unroll
        for (int q = 0; q < 4; ++q) {
            const int r = (l >> 4) * 4 + q;
            const float s2v = (float)lds_read1(S2s, r, 2048, k * 2);
            const float val = (acc[f][q] + s2v) * 0.125f + vm;
            acc[f][q] = val;
            mrow[q] = fmaxf(mrow[q], val);
        }
    }
    #pragma unroll
    for (int q = 0; q < 4; ++q) {
        float m = mrow[q];
        #pragma unroll
        for (int off = 1; off < 16; off <<= 1) m = fmaxf(m, __shfl_xor(m, off));
        mrow[q] = m;
    }
    if ((l & 15) == 0) {
        #pragma unroll
        for (int q = 0; q < 4; ++q) redm[w][(l >> 4) * 4 + q] = mrow[q];
    }
    __syncthreads();
    #pragma unroll
    for (int q = 0; q < 4; ++q) {
        const int r = (l >> 4) * 4 + q;
        mrow[q] = fmaxf(fmaxf(redm[0][r], redm[1][r]), fmaxf(redm[2][r], redm[3][r]));
    }

    float lsum[4] = {0.f, 0.f, 0.f, 0.f};
    #pragma unroll
    for (int f = 0; f < 16; ++f)
        #pragma unroll
        for (int q = 0; q < 4; ++q) {
            const float e = __expf(acc[f][q] - mrow[q]);
            acc[f][q] = e;
            lsum[q] += e;
        }
    #pragma unroll
    for (int q = 0; q < 4; ++q) {
        float s = lsum[q];
        #pragma unroll
        for (int off = 1; off < 16; off <<= 1) s += __shfl_xor(s, off);
        lsum[q] = s;
    }
    if ((l & 15) == 0) {
        #pragma unroll
        for (int q = 0; q < 4; ++q) reds[w][(l >> 4) * 4 + q] = lsum[q];
    }
    __syncthreads();
    #pragma unroll
    for (int q = 0; q < 4; ++q) {
        const int r = (l >> 4) * 4 + q;
        lsum[q] = 1.0f / (reds[0][r] + reds[1][r] + reds[2][r] + reds[3][r]);
    }

    #pragma unroll
    for (int q = 0; q < 4; ++q) {
        const int r = (l >> 4) * 4 + q;
        const size_t base = (size_t)bh * (512 * 1024) + (size_t)(jl0 + r) * 1024;
        #pragma unroll
        for (int f = 0; f < 16; ++f) {
            const int k = (f >> 1) * 128 + w * 32 + (f & 1) * 16 + (l & 15);
            S2A[base + k] = (f16)(acc[f][q] * lsum[q]);
        }
    }
}

// ---------------------------------------------------------------------------
// Pass 4a: O1 = A @ V (per bh, 64-j tile).  omid[b][j][h*64+d] = O1
// ---------------------------------------------------------------------------
__global__ __launch_bounds__(256) void av_gemm(
    const f16* __restrict__ A, const f16* __restrict__ Vb,
    float* __restrict__ omid, int jbase)
{
    const int bh = blockIdx.x, b = bh / H_, h = bh % H_;
    const int jl0 = blockIdx.y * 64;
    const int j0 = jbase + jl0;
    const int t = threadIdx.x, l = t & 63, w = t >> 6;

    __shared__ __attribute__((aligned(16))) f16 As[64 * 64];
    __shared__ __attribute__((aligned(16))) f16 Vt[64 * 64];   // transposed [d][k]

    f32x4 acc[4] = {};
    for (int kt = 0; kt < S_; kt += 64) {
        __syncthreads();
        for (int idx = t; idx < 64 * 8; idx += 256) {
            const int r = idx >> 3, c8 = idx & 7;
            f16x8 v = *(const f16x8*)(A + (size_t)bh * (512 * 1024) + (size_t)(jl0 + r) * 1024 + kt + c8 * 8);
            lds_write8(As, r, 128, c8 * 16, v);
        }
        for (int idx = t; idx < 64 * 8; idx += 256) {
            const int k = idx >> 3, d8 = (idx & 7) * 8;
            f16x8 v = *(const f16x8*)(Vb + ((size_t)bh * S_ + kt + k) * DK_ + d8);
            #pragma unroll
            for (int e = 0; e < 8; ++e) lds_write1(Vt, d8 + e, 128, k * 2, v[e]);
        }
        __syncthreads();
        #pragma unroll
        for (int ks = 0; ks < 2; ++ks) {
            const f16x8 a = lds_read8(As, w * 16 + (l & 15), 128, ks * 64 + (l >> 4) * 16);
            #pragma unroll
            for (int ni = 0; ni < 4; ++ni) {
                const f16x8 bv = lds_read8(Vt, ni * 16 + (l & 15), 128, ks * 64 + (l >> 4) * 16);
                acc[ni] = MFMA16(a, bv, acc[ni]);
            }
        }
    }

    #pragma unroll
    for (int ni = 0; ni < 4; ++ni)
        #pragma unroll
        for (int q = 0; q < 4; ++q) {
            const int j = j0 + w * 16 + (l >> 4) * 4 + q;
            const int d = ni * 16 + (l & 15);
            omid[((size_t)b * S_ + j) * D_ + h * DK_ + d] = acc[ni][q];
        }
}

// ---------------------------------------------------------------------------
// Pass 4b: O2 = A_j @ pb[j]  (per-j GEMM, M=96,N=64,K=1024).  omid += O2
// ---------------------------------------------------------------------------
__global__ __launch_bounds__(256) void apb_gemm(
    const f16* __restrict__ A, const float* __restrict__ pb,
    float* __restrict__ omid, int jbase)
{
    const int jl = blockIdx.x;
    const int j  = jbase + jl;
    const int t = threadIdx.x, l = t & 63, w = t >> 6;

    __shared__ __attribute__((aligned(16))) f16 As[96 * 64];
    __shared__ __attribute__((aligned(16))) f16 Pt[64 * 64];   // transposed [d][k]

    f32x4 acc[6] = {};
    for (int kt = 0; kt < S_; kt += 64) {
        __syncthreads();
        for (int idx = t; idx < 96 * 8; idx += 256) {
            const int r = idx >> 3, c8 = idx & 7;
            f16x8 v = *(const f16x8*)(A + (size_t)r * (512 * 1024) + (size_t)jl * 1024 + kt + c8 * 8);
            lds_write8(As, r, 128, c8 * 16, v);
        }
        for (int idx = t; idx < 64 * 16; idx += 256) {
            const int k = idx >> 4, d4 = (idx & 15) * 4;
            const float4 v = *(const float4*)(pb + ((size_t)j * S_ + kt + k) * DK_ + d4);
            lds_write1(Pt, d4 + 0, 128, k * 2, (f16)v.x);
            lds_write1(Pt, d4 + 1, 128, k * 2, (f16)v.y);
            lds_write1(Pt, d4 + 2, 128, k * 2, (f16)v.z);
            lds_write1(Pt, d4 + 3, 128, k * 2, (f16)v.w);
        }
        __syncthreads();
        #pragma unroll
        for (int ks = 0; ks < 2; ++ks) {
            const f16x8 bv = lds_read8(Pt, w * 16 + (l & 15), 128, ks * 64 + (l >> 4) * 16);
            #pragma unroll
            for (int mi = 0; mi < 6; ++mi) {
                const f16x8 a = lds_read8(As, mi * 16 + (l & 15), 128, ks * 64 + (l >> 4) * 16);
                acc[mi] = MFMA16(a, bv, acc[mi]);
            }
        }
    }

    #pragma unroll
    for (int mi = 0; mi < 6; ++mi)
        #pragma unroll
        for (int q = 0; q < 4; ++q) {
            const int bh = mi * 16 + (l >> 4) * 4 + q;
            const int b = bh / H_, h = bh % H_;
            const int d = w * 16 + (l & 15);
            const size_t o = ((size_t)b * S_ + j) * D_ + h * DK_ + d;
            omid[o] += acc[mi][q];
        }
}

// ---------------------------------------------------------------------------
// Pass 5: out = (omid @ Wo + bo) * q_mask   (fp32)
// ---------------------------------------------------------------------------
__global__ __launch_bounds__(256) void out_gemm(
    const float* __restrict__ a, const float* __restrict__ W,
    const float* __restrict__ bias, const float* __restrict__ qm,
    float* __restrict__ out)
{
    const int row0 = blockIdx.x * 64;
    const int col0 = blockIdx.y * 64;
    const int t  = threadIdx.x;
    const int tx = t & 15, ty = t >> 4;

    __shared__ __attribute__((aligned(16))) float Xs[64][17];
    __shared__ __attribute__((aligned(16))) float Ws[16][68];

    float acc[4][4] = {};

    for (int kt = 0; kt < D_; kt += 16) {
        {
            const int r = t >> 2, c = (t & 3) * 4;
            const float4 xv = *(const float4*)&a[(size_t)(row0 + r) * D_ + kt + c];
            Xs[r][c] = xv.x; Xs[r][c+1] = xv.y; Xs[r][c+2] = xv.z; Xs[r][c+3] = xv.w;
        }
        {
            const int r = t >> 4, c = (t & 15) * 4;
            const float4 wv = *(const float4*)&W[(size_t)(kt + r) * D_ + col0 + c];
            Ws[r][c] = wv.x; Ws[r][c+1] = wv.y; Ws[r][c+2] = wv.z; Ws[r][c+3] = wv.w;
        }
        __syncthreads();
        #pragma unroll
        for (int kk = 0; kk < 16; ++kk) {
            float xr[4], wc[4];
            #pragma unroll
            for (int i = 0; i < 4; ++i) xr[i] = Xs[ty*4+i][kk];
            #pragma unroll
            for (int j = 0; j < 4; ++j) wc[j] = Ws[kk][tx*4+j];
            #pragma unroll
            for (int i = 0; i < 4; ++i)
                #pragma unroll
                for (int j = 0; j < 4; ++j)
                    acc[i][j] += xr[i] * wc[j];
        }
        __syncthreads();
    }

    #pragma unroll
    for (int i = 0; i < 4; ++i) {
        const int row = row0 + ty*4 + i;
        const float qmv = qm[row];
        #pragma unroll
        for (int j = 0; j < 4; ++j) {
            const int col = col0 + tx*4 + j;
            out[(size_t)row * D_ + col] = (acc[i][j] + bias[col]) * qmv;
        }
    }
}

extern "C" void kernel_launch(void* const* d_in, const int* in_sizes, int n_in,
                              void* d_out, int out_size, void* d_ws, size_t ws_size,
                              hipStream_t stream) {
    const float* x  = (const float*)d_in[0];
    const float* Wq = (const float*)d_in[1];
    const float* bq = (const float*)d_in[2];
    const float* Wk = (const float*)d_in[3];
    const float* bk = (const float*)d_in[4];
    const float* Wv = (const float*)d_in[5];
    const float* bv = (const float*)d_in[6];
    const float* Wo = (const float*)d_in[7];
    const float* bo = (const float*)d_in[8];
    const float* pb = (const float*)d_in[9];
    const float* qm = (const float*)d_in[10];
    const float* vm = (const float*)d_in[11];
    float* out = (float*)d_out;

    const size_t NQ = (size_t)BH_ * S_ * DK_;          // 6,291,456 halfs
    f16* qb = (f16*)d_ws;
    f16* kb = qb + NQ;
    f16* vb = kb + NQ;
    f16* s2 = vb + NQ;                                  // 96*512*1024 halfs (100.7 MB)
    float* omid = (float*)(s2 + (size_t)BH_ * 512 * 1024);  // 8192*768 fp32 (25.2 MB)

    dim3 g1(128, 12, 3);
    qkv_gemm<<<g1, 256, 0, stream>>>(x, Wq, bq, Wk, bk, Wv, bv, qb, kb, vb);

    for (int half = 0; half < 2; ++half) {
        const int jbase = half * 512;
        s2_gemm <<<dim3(512, 4), 256, 0, stream>>>(qb, pb, s2, jbase);
        attn_sm <<<dim3(96, 32), 256, 0, stream>>>(qb, kb, vm, s2, jbase);
        av_gemm <<<dim3(96, 8),  256, 0, stream>>>(s2, vb, omid, jbase);
        apb_gemm<<<dim3(512),    256, 0, stream>>>(s2, pb, omid, jbase);
    }

    dim3 g3(128, 12);
    out_gemm<<<g3, 256, 0, stream>>>(omid, Wo, bo, qm, out);
}

// Round 3
// 626.132 us; speedup vs baseline: 10.9979x; 1.7289x over previous
//
#include <hip/hip_runtime.h>

#define B_  8
#define S_  1024
#define D_  768
#define H_  12
#define DK_ 64
#define BH_ 96

typedef _Float16 f16;
typedef _Float16 f16x8 __attribute__((ext_vector_type(8)));
typedef _Float16 f16x4 __attribute__((ext_vector_type(4)));
typedef float    f32x4 __attribute__((ext_vector_type(4)));

#define MFMA16(a, b, c) __builtin_amdgcn_mfma_f32_16x16x32_f16((a), (b), (c), 0, 0, 0)

// ---- LDS swizzle helpers: XOR bits 4..6 of byte offset with f(row) ---------
__device__ __forceinline__ int swz(int row) { return ((row ^ (row >> 3)) & 7) << 4; }

__device__ __forceinline__ f16x8 lds_read8(const f16* base, int row, int rowbytes, int colbyte) {
    const char* p = (const char*)base + row * rowbytes + (colbyte ^ swz(row));
    return *(const f16x8*)p;
}
__device__ __forceinline__ void lds_write8(f16* base, int row, int rowbytes, int colbyte, f16x8 v) {
    char* p = (char*)base + row * rowbytes + (colbyte ^ swz(row));
    *(f16x8*)p = v;
}
__device__ __forceinline__ void lds_write4(f16* base, int row, int rowbytes, int colbyte, f16x4 v) {
    char* p = (char*)base + row * rowbytes + (colbyte ^ swz(row));
    *(f16x4*)p = v;
}
__device__ __forceinline__ void lds_write1(f16* base, int row, int rowbytes, int colbyte, f16 v) {
    char* p = (char*)base + row * rowbytes + (colbyte ^ swz(row));
    *(f16*)p = v;
}
__device__ __forceinline__ f16 lds_read1(const f16* base, int row, int rowbytes, int colbyte) {
    const char* p = (const char*)base + row * rowbytes + (colbyte ^ swz(row));
    return *(const f16*)p;
}

// ---------------------------------------------------------------------------
// Prep A: x fp32 -> f16 (flat copy, float4-vectorized)
// ---------------------------------------------------------------------------
__global__ __launch_bounds__(256) void cvt_x(const float* __restrict__ in,
                                             f16* __restrict__ out, int n4)
{
    const int i = blockIdx.x * 256 + threadIdx.x;
    if (i < n4) {
        const float4 v = ((const float4*)in)[i];
        f16x4 h; h[0] = (f16)v.x; h[1] = (f16)v.y; h[2] = (f16)v.z; h[3] = (f16)v.w;
        ((f16x4*)out)[i] = h;
    }
}

// ---------------------------------------------------------------------------
// Prep B: W [k][n] fp32 -> WT [n][k] f16 (tiled transpose via LDS)
// ---------------------------------------------------------------------------
__global__ __launch_bounds__(256) void wT_cvt(
    const float* __restrict__ Wq, const float* __restrict__ Wk,
    const float* __restrict__ Wv, const float* __restrict__ Wo,
    f16* __restrict__ Tq, f16* __restrict__ Tk,
    f16* __restrict__ Tv, f16* __restrict__ To)
{
    const float* W; f16* T;
    if      (blockIdx.z == 0) { W = Wq; T = Tq; }
    else if (blockIdx.z == 1) { W = Wk; T = Tk; }
    else if (blockIdx.z == 2) { W = Wv; T = Tv; }
    else                      { W = Wo; T = To; }

    const int r0 = blockIdx.x * 32;   // k
    const int c0 = blockIdx.y * 32;   // n
    const int t = threadIdx.x, tx = t & 31, ty = t >> 5;

    __shared__ float tile[32][33];
    #pragma unroll
    for (int i = 0; i < 4; ++i)
        tile[ty + 8 * i][tx] = W[(size_t)(r0 + ty + 8 * i) * D_ + c0 + tx];
    __syncthreads();
    #pragma unroll
    for (int i = 0; i < 4; ++i)
        T[(size_t)(c0 + ty + 8 * i) * D_ + r0 + tx] = (f16)tile[tx][ty + 8 * i];
}

// ---------------------------------------------------------------------------
// Pass 1: QKV projection, f16 MFMA. C[row,col]=x16[row,:]@WT[col,:]+b[col].
// 128x128 tile, BK=64, 4 waves each computing a 64x64 quadrant.
// Output f16 in [bh][s][64] layout.
// ---------------------------------------------------------------------------
__global__ __launch_bounds__(256) void qkv_mfma(
    const f16* __restrict__ x16,
    const f16* __restrict__ Tq, const f16* __restrict__ Tk, const f16* __restrict__ Tv,
    const float* __restrict__ bq, const float* __restrict__ bk, const float* __restrict__ bv,
    f16* __restrict__ qo, f16* __restrict__ ko, f16* __restrict__ vo)
{
    const f16* WT; const float* bias; f16* out;
    if      (blockIdx.z == 0) { WT = Tq; bias = bq; out = qo; }
    else if (blockIdx.z == 1) { WT = Tk; bias = bk; out = ko; }
    else                      { WT = Tv; bias = bv; out = vo; }

    const int row0 = blockIdx.x * 128;
    const int col0 = blockIdx.y * 128;
    const int t = threadIdx.x, l = t & 63, w = t >> 6;
    const int wr = w >> 1, wc = w & 1;

    __shared__ __attribute__((aligned(16))) f16 As[128 * 64];  // [m][k] rowbytes 128
    __shared__ __attribute__((aligned(16))) f16 Bs[128 * 64];  // [n][k] rowbytes 128

    f32x4 acc[4][4] = {};

    for (int kt = 0; kt < D_; kt += 64) {
        __syncthreads();
        #pragma unroll
        for (int ii = 0; ii < 4; ++ii) {
            const int idx = t + ii * 256;
            const int r = idx >> 3, c8 = idx & 7;
            f16x8 v = *(const f16x8*)(x16 + (size_t)(row0 + r) * D_ + kt + c8 * 8);
            lds_write8(As, r, 128, c8 * 16, v);
        }
        #pragma unroll
        for (int ii = 0; ii < 4; ++ii) {
            const int idx = t + ii * 256;
            const int r = idx >> 3, c8 = idx & 7;
            f16x8 v = *(const f16x8*)(WT + (size_t)(col0 + r) * D_ + kt + c8 * 8);
            lds_write8(Bs, r, 128, c8 * 16, v);
        }
        __syncthreads();
        #pragma unroll
        for (int ks = 0; ks < 2; ++ks) {
            f16x8 af[4], bf[4];
            #pragma unroll
            for (int mi = 0; mi < 4; ++mi)
                af[mi] = lds_read8(As, wr * 64 + mi * 16 + (l & 15), 128, ks * 64 + (l >> 4) * 16);
            #pragma unroll
            for (int ni = 0; ni < 4; ++ni)
                bf[ni] = lds_read8(Bs, wc * 64 + ni * 16 + (l & 15), 128, ks * 64 + (l >> 4) * 16);
            #pragma unroll
            for (int mi = 0; mi < 4; ++mi)
                #pragma unroll
                for (int ni = 0; ni < 4; ++ni)
                    acc[mi][ni] = MFMA16(af[mi], bf[ni], acc[mi][ni]);
        }
    }

    #pragma unroll
    for (int mi = 0; mi < 4; ++mi)
        #pragma unroll
        for (int q = 0; q < 4; ++q) {
            const int row = row0 + wr * 64 + mi * 16 + (l >> 4) * 4 + q;
            const int b = row >> 10, s = row & 1023;
            #pragma unroll
            for (int ni = 0; ni < 4; ++ni) {
                const int col = col0 + wc * 64 + ni * 16 + (l & 15);
                const int h = col >> 6, dk = col & 63;
                out[(((size_t)(b * H_ + h)) * S_ + s) * DK_ + dk] = (f16)(acc[mi][ni][q] + bias[col]);
            }
        }
}

// ---------------------------------------------------------------------------
// Pass 2: S2[bh][j][k] = Q[bh,j,:] . pb[j,k,:]  (per-j GEMM, M=96,N=1024,K=64)
// ---------------------------------------------------------------------------
__global__ __launch_bounds__(256) void s2_gemm(
    const f16* __restrict__ Qb, const float* __restrict__ pb,
    f16* __restrict__ S2, int jbase)
{
    const int jl = blockIdx.x;
    const int j  = jbase + jl;
    const int n0 = blockIdx.y * 256;
    const int t = threadIdx.x, l = t & 63, w = t >> 6;

    __shared__ __attribute__((aligned(16))) f16 Qs[96 * 64];
    __shared__ __attribute__((aligned(16))) f16 Ps[256 * 64];

    for (int idx = t; idx < 96 * 8; idx += 256) {
        const int r = idx >> 3, c8 = idx & 7;
        f16x8 v = *(const f16x8*)(Qb + ((size_t)r * S_ + j) * DK_ + c8 * 8);
        lds_write8(Qs, r, 128, c8 * 16, v);
    }
    for (int idx = t; idx < 256 * 16; idx += 256) {
        const int r = idx >> 4, c4 = idx & 15;
        const float4 v = *(const float4*)(pb + ((size_t)j * S_ + n0 + r) * DK_ + c4 * 4);
        f16x4 h; h[0] = (f16)v.x; h[1] = (f16)v.y; h[2] = (f16)v.z; h[3] = (f16)v.w;
        lds_write4(Ps, r, 128, c4 * 8, h);
    }
    __syncthreads();

    f32x4 acc[6][4] = {};
    #pragma unroll
    for (int s = 0; s < 4; ++s) {
        const int nrow = w * 64 + s * 16 + (l & 15);
        const f16x8 b0 = lds_read8(Ps, nrow, 128, (l >> 4) * 16);
        const f16x8 b1 = lds_read8(Ps, nrow, 128, 64 + (l >> 4) * 16);
        #pragma unroll
        for (int mi = 0; mi < 6; ++mi) {
            const int mrow = mi * 16 + (l & 15);
            const f16x8 a0 = lds_read8(Qs, mrow, 128, (l >> 4) * 16);
            const f16x8 a1 = lds_read8(Qs, mrow, 128, 64 + (l >> 4) * 16);
            acc[mi][s] = MFMA16(a0, b0, acc[mi][s]);
            acc[mi][s] = MFMA16(a1, b1, acc[mi][s]);
        }
    }

    #pragma unroll
    for (int mi = 0; mi < 6; ++mi)
        #pragma unroll
        for (int q = 0; q < 4; ++q) {
            const int bh = mi * 16 + (l >> 4) * 4 + q;
            const size_t base = (size_t)bh * (512 * 1024) + (size_t)jl * 1024;
            #pragma unroll
            for (int s = 0; s < 4; ++s) {
                const int k = n0 + w * 64 + s * 16 + (l & 15);
                S2[base + k] = (f16)acc[mi][s][q];
            }
        }
}

// ---------------------------------------------------------------------------
// Pass 3: scores = (QK^T + S2)/8 + mask; exact softmax; normalized A in place.
// ---------------------------------------------------------------------------
__global__ __launch_bounds__(256) void attn_sm(
    const f16* __restrict__ Qb, const f16* __restrict__ Kb,
    const float* __restrict__ vmask, f16* __restrict__ S2A, int jbase)
{
    const int bh = blockIdx.x, b = bh / H_;
    const int jl0 = blockIdx.y * 16;
    const int j0 = jbase + jl0;
    const int t = threadIdx.x, l = t & 63, w = t >> 6;

    __shared__ __attribute__((aligned(16))) f16 Ks[128 * 64];
    __shared__ __attribute__((aligned(16))) f16 S2s[16 * 1024];
    __shared__ float vmneg[1024];
    __shared__ float redm[4][16], reds[4][16];

    for (int idx = t; idx < 16 * 128; idx += 256) {
        const int r = idx >> 7, c8 = idx & 127;
        f16x8 v = *(const f16x8*)(S2A + (size_t)bh * (512 * 1024) + (size_t)(jl0 + r) * 1024 + c8 * 8);
        lds_write8(S2s, r, 2048, c8 * 16, v);
    }
    for (int k = t; k < 1024; k += 256)
        vmneg[k] = (vmask[(size_t)b * S_ + k] - 1.0f) * 1e12f;

    const f16x8 aq0 = *(const f16x8*)(Qb + ((size_t)bh * S_ + j0 + (l & 15)) * DK_ + (l >> 4) * 8);
    const f16x8 aq1 = *(const f16x8*)(Qb + ((size_t)bh * S_ + j0 + (l & 15)) * DK_ + 32 + (l >> 4) * 8);

    f32x4 acc[16] = {};
    #pragma unroll
    for (int c = 0; c < 8; ++c) {
        __syncthreads();
        for (int idx = t; idx < 128 * 8; idx += 256) {
            const int r = idx >> 3, c8 = idx & 7;
            f16x8 v = *(const f16x8*)(Kb + ((size_t)bh * S_ + c * 128 + r) * DK_ + c8 * 8);
            lds_write8(Ks, r, 128, c8 * 16, v);
        }
        __syncthreads();
        #pragma unroll
        for (int s = 0; s < 2; ++s) {
            const int krow = w * 32 + s * 16 + (l & 15);
            const f16x8 b0 = lds_read8(Ks, krow, 128, (l >> 4) * 16);
            const f16x8 b1 = lds_read8(Ks, krow, 128, 64 + (l >> 4) * 16);
            acc[c * 2 + s] = MFMA16(aq0, b0, acc[c * 2 + s]);
            acc[c * 2 + s] = MFMA16(aq1, b1, acc[c * 2 + s]);
        }
    }

    float mrow[4] = {-3e38f, -3e38f, -3e38f, -3e38f};
    #pragma unroll
    for (int f = 0; f < 16; ++f) {
        const int k = (f >> 1) * 128 + w * 32 + (f & 1) * 16 + (l & 15);
        const float vm = vmneg[k];
        #pragma unroll
        for (int q = 0; q < 4; ++q) {
            const int r = (l >> 4) * 4 + q;
            const float s2v = (float)lds_read1(S2s, r, 2048, k * 2);
            const float val = (acc[f][q] + s2v) * 0.125f + vm;
            acc[f][q] = val;
            mrow[q] = fmaxf(mrow[q], val);
        }
    }
    #pragma unroll
    for (int q = 0; q < 4; ++q) {
        float m = mrow[q];
        #pragma unroll
        for (int off = 1; off < 16; off <<= 1) m = fmaxf(m, __shfl_xor(m, off));
        mrow[q] = m;
    }
    if ((l & 15) == 0) {
        #pragma unroll
        for (int q = 0; q < 4; ++q) redm[w][(l >> 4) * 4 + q] = mrow[q];
    }
    __syncthreads();
    #pragma unroll
    for (int q = 0; q < 4; ++q) {
        const int r = (l >> 4) * 4 + q;
        mrow[q] = fmaxf(fmaxf(redm[0][r], redm[1][r]), fmaxf(redm[2][r], redm[3][r]));
    }

    float lsum[4] = {0.f, 0.f, 0.f, 0.f};
    #pragma unroll
    for (int f = 0; f < 16; ++f)
        #pragma unroll
        for (int q = 0; q < 4; ++q) {
            const float e = __expf(acc[f][q] - mrow[q]);
            acc[f][q] = e;
            lsum[q] += e;
        }
    #pragma unroll
    for (int q = 0; q < 4; ++q) {
        float s = lsum[q];
        #pragma unroll
        for (int off = 1; off < 16; off <<= 1) s += __shfl_xor(s, off);
        lsum[q] = s;
    }
    if ((l & 15) == 0) {
        #pragma unroll
        for (int q = 0; q < 4; ++q) reds[w][(l >> 4) * 4 + q] = lsum[q];
    }
    __syncthreads();
    #pragma unroll
    for (int q = 0; q < 4; ++q) {
        const int r = (l >> 4) * 4 + q;
        lsum[q] = 1.0f / (reds[0][r] + reds[1][r] + reds[2][r] + reds[3][r]);
    }

    #pragma unroll
    for (int q = 0; q < 4; ++q) {
        const int r = (l >> 4) * 4 + q;
        const size_t base = (size_t)bh * (512 * 1024) + (size_t)(jl0 + r) * 1024;
        #pragma unroll
        for (int f = 0; f < 16; ++f) {
            const int k = (f >> 1) * 128 + w * 32 + (f & 1) * 16 + (l & 15);
            S2A[base + k] = (f16)(acc[f][q] * lsum[q]);
        }
    }
}

// ---------------------------------------------------------------------------
// Pass 4a: O1 = A @ V (per bh, 64-j tile) -> omid fp32
// ---------------------------------------------------------------------------
__global__ __launch_bounds__(256) void av_gemm(
    const f16* __restrict__ A, const f16* __restrict__ Vb,
    float* __restrict__ omid, int jbase)
{
    const int bh = blockIdx.x, b = bh / H_, h = bh % H_;
    const int jl0 = blockIdx.y * 64;
    const int j0 = jbase + jl0;
    const int t = threadIdx.x, l = t & 63, w = t >> 6;

    __shared__ __attribute__((aligned(16))) f16 As[64 * 64];
    __shared__ __attribute__((aligned(16))) f16 Vt[64 * 64];

    f32x4 acc[4] = {};
    for (int kt = 0; kt < S_; kt += 64) {
        __syncthreads();
        for (int idx = t; idx < 64 * 8; idx += 256) {
            const int r = idx >> 3, c8 = idx & 7;
            f16x8 v = *(const f16x8*)(A + (size_t)bh * (512 * 1024) + (size_t)(jl0 + r) * 1024 + kt + c8 * 8);
            lds_write8(As, r, 128, c8 * 16, v);
        }
        for (int idx = t; idx < 64 * 8; idx += 256) {
            const int k = idx >> 3, d8 = (idx & 7) * 8;
            f16x8 v = *(const f16x8*)(Vb + ((size_t)bh * S_ + kt + k) * DK_ + d8);
            #pragma unroll
            for (int e = 0; e < 8; ++e) lds_write1(Vt, d8 + e, 128, k * 2, v[e]);
        }
        __syncthreads();
        #pragma unroll
        for (int ks = 0; ks < 2; ++ks) {
            const f16x8 a = lds_read8(As, w * 16 + (l & 15), 128, ks * 64 + (l >> 4) * 16);
            #pragma unroll
            for (int ni = 0; ni < 4; ++ni) {
                const f16x8 bv = lds_read8(Vt, ni * 16 + (l & 15), 128, ks * 64 + (l >> 4) * 16);
                acc[ni] = MFMA16(a, bv, acc[ni]);
            }
        }
    }

    #pragma unroll
    for (int ni = 0; ni < 4; ++ni)
        #pragma unroll
        for (int q = 0; q < 4; ++q) {
            const int j = j0 + w * 16 + (l >> 4) * 4 + q;
            const int d = ni * 16 + (l & 15);
            omid[((size_t)b * S_ + j) * D_ + h * DK_ + d] = acc[ni][q];
        }
}

// ---------------------------------------------------------------------------
// Pass 4b: O2 = A_j @ pb[j] (per-j GEMM); writes omid16 = f16(omid + O2)
// ---------------------------------------------------------------------------
__global__ __launch_bounds__(256) void apb_gemm(
    const f16* __restrict__ A, const float* __restrict__ pb,
    const float* __restrict__ omid, f16* __restrict__ omid16, int jbase)
{
    const int jl = blockIdx.x;
    const int j  = jbase + jl;
    const int t = threadIdx.x, l = t & 63, w = t >> 6;

    __shared__ __attribute__((aligned(16))) f16 As[96 * 64];
    __shared__ __attribute__((aligned(16))) f16 Pt[64 * 64];

    f32x4 acc[6] = {};
    for (int kt = 0; kt < S_; kt += 64) {
        __syncthreads();
        for (int idx = t; idx < 96 * 8; idx += 256) {
            const int r = idx >> 3, c8 = idx & 7;
            f16x8 v = *(const f16x8*)(A + (size_t)r * (512 * 1024) + (size_t)jl * 1024 + kt + c8 * 8);
            lds_write8(As, r, 128, c8 * 16, v);
        }
        for (int idx = t; idx < 64 * 16; idx += 256) {
            const int k = idx >> 4, d4 = (idx & 15) * 4;
            const float4 v = *(const float4*)(pb + ((size_t)j * S_ + kt + k) * DK_ + d4);
            lds_write1(Pt, d4 + 0, 128, k * 2, (f16)v.x);
            lds_write1(Pt, d4 + 1, 128, k * 2, (f16)v.y);
            lds_write1(Pt, d4 + 2, 128, k * 2, (f16)v.z);
            lds_write1(Pt, d4 + 3, 128, k * 2, (f16)v.w);
        }
        __syncthreads();
        #pragma unroll
        for (int ks = 0; ks < 2; ++ks) {
            const f16x8 bv = lds_read8(Pt, w * 16 + (l & 15), 128, ks * 64 + (l >> 4) * 16);
            #pragma unroll
            for (int mi = 0; mi < 6; ++mi) {
                const f16x8 a = lds_read8(As, mi * 16 + (l & 15), 128, ks * 64 + (l >> 4) * 16);
                acc[mi] = MFMA16(a, bv, acc[mi]);
            }
        }
    }

    #pragma unroll
    for (int mi = 0; mi < 6; ++mi)
        #pragma unroll
        for (int q = 0; q < 4; ++q) {
            const int bh = mi * 16 + (l >> 4) * 4 + q;
            const int b = bh / H_, h = bh % H_;
            const int d = w * 16 + (l & 15);
            const size_t o = ((size_t)b * S_ + j) * D_ + h * DK_ + d;
            omid16[o] = (f16)(omid[o] + acc[mi][q]);
        }
}

// ---------------------------------------------------------------------------
// Pass 5: out = (omid16 @ WoT^T + bo) * q_mask, f16 MFMA, fp32 out
// ---------------------------------------------------------------------------
__global__ __launch_bounds__(256) void out_mfma(
    const f16* __restrict__ a16, const f16* __restrict__ WT,
    const float* __restrict__ bias, const float* __restrict__ qm,
    float* __restrict__ out)
{
    const int row0 = blockIdx.x * 128;
    const int col0 = blockIdx.y * 128;
    const int t = threadIdx.x, l = t & 63, w = t >> 6;
    const int wr = w >> 1, wc = w & 1;

    __shared__ __attribute__((aligned(16))) f16 As[128 * 64];
    __shared__ __attribute__((aligned(16))) f16 Bs[128 * 64];

    f32x4 acc[4][4] = {};

    for (int kt = 0; kt < D_; kt += 64) {
        __syncthreads();
        #pragma unroll
        for (int ii = 0; ii < 4; ++ii) {
            const int idx = t + ii * 256;
            const int r = idx >> 3, c8 = idx & 7;
            f16x8 v = *(const f16x8*)(a16 + (size_t)(row0 + r) * D_ + kt + c8 * 8);
            lds_write8(As, r, 128, c8 * 16, v);
        }
        #pragma unroll
        for (int ii = 0; ii < 4; ++ii) {
            const int idx = t + ii * 256;
            const int r = idx >> 3, c8 = idx & 7;
            f16x8 v = *(const f16x8*)(WT + (size_t)(col0 + r) * D_ + kt + c8 * 8);
            lds_write8(Bs, r, 128, c8 * 16, v);
        }
        __syncthreads();
        #pragma unroll
        for (int ks = 0; ks < 2; ++ks) {
            f16x8 af[4], bf[4];
            #pragma unroll
            for (int mi = 0; mi < 4; ++mi)
                af[mi] = lds_read8(As, wr * 64 + mi * 16 + (l & 15), 128, ks * 64 + (l >> 4) * 16);
            #pragma unroll
            for (int ni = 0; ni < 4; ++ni)
                bf[ni] = lds_read8(Bs, wc * 64 + ni * 16 + (l & 15), 128, ks * 64 + (l >> 4) * 16);
            #pragma unroll
            for (int mi = 0; mi < 4; ++mi)
                #pragma unroll
                for (int ni = 0; ni < 4; ++ni)
                    acc[mi][ni] = MFMA16(af[mi], bf[ni], acc[mi][ni]);
        }
    }

    #pragma unroll
    for (int mi = 0; mi < 4; ++mi)
        #pragma unroll
        for (int q = 0; q < 4; ++q) {
            const int row = row0 + wr * 64 + mi * 16 + (l >> 4) * 4 + q;
            const float qmv = qm[row];
            #pragma unroll
            for (int ni = 0; ni < 4; ++ni) {
                const int col = col0 + wc * 64 + ni * 16 + (l & 15);
                out[(size_t)row * D_ + col] = (acc[mi][ni][q] + bias[col]) * qmv;
            }
        }
}

extern "C" void kernel_launch(void* const* d_in, const int* in_sizes, int n_in,
                              void* d_out, int out_size, void* d_ws, size_t ws_size,
                              hipStream_t stream) {
    const float* x  = (const float*)d_in[0];
    const float* Wq = (const float*)d_in[1];
    const float* bq = (const float*)d_in[2];
    const float* Wk = (const float*)d_in[3];
    const float* bk = (const float*)d_in[4];
    const float* Wv = (const float*)d_in[5];
    const float* bv = (const float*)d_in[6];
    const float* Wo = (const float*)d_in[7];
    const float* bo = (const float*)d_in[8];
    const float* pb = (const float*)d_in[9];
    const float* qm = (const float*)d_in[10];
    const float* vm = (const float*)d_in[11];
    float* out = (float*)d_out;

    const size_t NQ = (size_t)BH_ * S_ * DK_;          // 6,291,456 halfs
    const size_t NW = (size_t)D_ * D_;                 // 589,824
    f16* qb = (f16*)d_ws;
    f16* kb = qb + NQ;
    f16* vb = kb + NQ;
    f16* s2 = vb + NQ;                                  // 96*512*1024 halfs (100.7 MB)
    f16* x16 = s2 + (size_t)BH_ * 512 * 1024;
    f16* tq  = x16 + (size_t)B_ * S_ * D_;
    f16* tk  = tq + NW;
    f16* tv  = tk + NW;
    f16* to  = tv + NW;
    f16* omid16 = to + NW;                              // 8192*768 f16
    float* omid = (float*)(omid16 + (size_t)B_ * S_ * D_);  // 8192*768 fp32

    cvt_x<<<dim3((B_ * S_ * D_ / 4 + 255) / 256), 256, 0, stream>>>(x, x16, B_ * S_ * D_ / 4);
    wT_cvt<<<dim3(24, 24, 4), 256, 0, stream>>>(Wq, Wk, Wv, Wo, tq, tk, tv, to);

    qkv_mfma<<<dim3(64, 6, 3), 256, 0, stream>>>(x16, tq, tk, tv, bq, bk, bv, qb, kb, vb);

    for (int half = 0; half < 2; ++half) {
        const int jbase = half * 512;
        s2_gemm <<<dim3(512, 4), 256, 0, stream>>>(qb, pb, s2, jbase);
        attn_sm <<<dim3(96, 32), 256, 0, stream>>>(qb, kb, vm, s2, jbase);
        av_gemm <<<dim3(96, 8),  256, 0, stream>>>(s2, vb, omid, jbase);
        apb_gemm<<<dim3(512),    256, 0, stream>>>(s2, pb, omid, omid16, jbase);
    }

    out_mfma<<<dim3(64, 6), 256, 0, stream>>>(omid16, to, bo, qm, out);
}